// Round 8
// baseline (186.082 us; speedup 1.0000x reference)
//
#include <hip/hip_runtime.h>

typedef unsigned short u16;
typedef unsigned int   u32;
typedef __bf16 bf16x8 __attribute__((ext_vector_type(8)));
typedef float  f32x4  __attribute__((ext_vector_type(4)));

// Geometry (fixed): b=32, h=w=56, C=192, NH=6, hd=32, WS=7, shift=3
// 2048 windows, 49 tokens (padded to 64).
// V8: 3-way split (ablation + per-phase occupancy shaping).
//   A: gather+QKV  2048 blocks, LDS 25.6KB, 1 barrier
//   B: attention   12288 units, 1 wave/unit, 0 barriers, LDS 18.4KB
//   C: proj        2048 blocks, 0 LDS

__device__ __forceinline__ u16 f2b(float f){
  return __builtin_bit_cast(u16, (__bf16)f);
}
__device__ __forceinline__ u32 pk2(float a, float b){
  return (u32)f2b(a) | ((u32)f2b(b) << 16);
}

__device__ __forceinline__ int coords_fn(int t){ return (t/7)*13 + (t%7); }
__device__ __forceinline__ int code_fn(int t, int wy, int wx){
  const int ty = t/7, tx = t%7;
  const int hp = wy*7 + ty, wp = wx*7 + tx;
  const int rh = (hp < 49) ? 0 : ((hp < 53) ? 1 : 2);
  const int rw = (wp < 49) ? 0 : ((wp < 53) ? 1 : 2);
  return rh*3 + rw;
}

// prep: weights fp32->bf16; biasC[cls][h][i][j] = rpb + (-100 shift mask) + (-1e30 j>=49)
__global__ __launch_bounds__(256) void prep_kernel(const float* __restrict__ qkvw,
                                                   const float* __restrict__ projw,
                                                   const float* __restrict__ rpb,
                                                   u16* __restrict__ wq, u16* __restrict__ wp,
                                                   float* __restrict__ biasC){
  const int i = blockIdx.x * 256 + threadIdx.x;   // 432*256 = 110592
  if (i < 576*192) wq[i] = f2b(qkvw[i]);
  if (i < 192*192) wp[i] = f2b(projw[i]);
  {
    const int cls = i / 27648, rem = i % 27648;
    const int h = rem / 4608, rem2 = rem % 4608;
    const int ii = rem2 / 72, j = rem2 % 72;
    const int wyR = (cls & 2) ? 7 : 0, wxR = (cls & 1) ? 7 : 0;
    float v = -1e30f;
    if (j < 49){
      const int icl = (ii > 48) ? 48 : ii;
      v = rpb[(coords_fn(icl) + coords_fn(48 - j))*6 + h];
      if (code_fn(icl, wyR, wxR) != code_fn(j, wyR, wxR)) v -= 100.0f;
    }
    biasC[i] = v;
  }
}

// ---------------- A: roll + gather + QKV GEMM -> qG/kG/vG ----------------
__global__ __launch_bounds__(256, 4) void qkv_kernel(const float* __restrict__ x,
    const u16* __restrict__ wq, const float* __restrict__ qb,
    u16* __restrict__ qG, u16* __restrict__ kG, u16* __restrict__ vG)
{
  __shared__ u16 XA[64][200];
  const int wi = blockIdx.x;
  const int bb = wi >> 6, wy = (wi >> 3) & 7, wx = wi & 7;
  const int tid = threadIdx.x;
  const int wave = tid >> 6, lane = tid & 63;
  const int g = lane >> 4, r = lane & 15;
  const f32x4 z4 = {0.f, 0.f, 0.f, 0.f};

  for (int it = tid; it < 64*48; it += 256){
    const int row = it / 48, c4 = (it % 48) * 4;
    u32 p0 = 0, p1 = 0;
    if (row < 49){
      const int ty = row / 7, tx = row % 7;
      int sh = wy*7 + ty + 3; if (sh >= 56) sh -= 56;
      int sw = wx*7 + tx + 3; if (sw >= 56) sw -= 56;
      const float4 f = *reinterpret_cast<const float4*>(x + (size_t)(((bb*56 + sh)*56 + sw))*192 + c4);
      p0 = pk2(f.x, f.y);
      p1 = pk2(f.z, f.w);
    }
    u32* dst = reinterpret_cast<u32*>(&XA[row][c4]);
    dst[0] = p0; dst[1] = p1;
  }
  __syncthreads();   // only barrier

  // ---- v (normal MFMA) -> vG[u][d][tok] ----
  {
    f32x4 va[4][3];
    #pragma unroll
    for (int mt = 0; mt < 4; ++mt)
      #pragma unroll
      for (int nt = 0; nt < 3; ++nt) va[mt][nt] = z4;
    #pragma unroll
    for (int ks = 0; ks < 6; ++ks){
      bf16x8 ax[4];
      #pragma unroll
      for (int mt = 0; mt < 4; ++mt)
        ax[mt] = *reinterpret_cast<const bf16x8*>(&XA[mt*16 + r][ks*32 + 8*g]);
      #pragma unroll
      for (int nt = 0; nt < 3; ++nt){
        const bf16x8 bw = *reinterpret_cast<const bf16x8*>(wq + (size_t)(384 + wave*48 + nt*16 + r)*192 + ks*32 + 8*g);
        #pragma unroll
        for (int mt = 0; mt < 4; ++mt)
          va[mt][nt] = __builtin_amdgcn_mfma_f32_16x16x32_bf16(ax[mt], bw, va[mt][nt], 0, 0, 0);
      }
    }
    #pragma unroll
    for (int nt = 0; nt < 3; ++nt){
      const int ch = wave*48 + nt*16 + r;
      const float bv = qb[384 + ch];
      const size_t ubase = ((size_t)(wi*6 + (ch >> 5))*32 + (ch & 31))*64;
      #pragma unroll
      for (int mt = 0; mt < 4; ++mt){
        uint2 t;
        t.x = pk2(va[mt][nt][0] + bv, va[mt][nt][1] + bv);
        t.y = pk2(va[mt][nt][2] + bv, va[mt][nt][3] + bv);
        *reinterpret_cast<uint2*>(vG + ubase + mt*16 + 4*g) = t;
      }
    }
  }

  // ---- q (swapped MFMA) -> qG[u][tok][32], scaled ----
  {
    f32x4 qa[3][4];
    #pragma unroll
    for (int c = 0; c < 3; ++c)
      #pragma unroll
      for (int tt = 0; tt < 4; ++tt) qa[c][tt] = z4;
    #pragma unroll
    for (int ks = 0; ks < 6; ++ks){
      bf16x8 aw[3];
      #pragma unroll
      for (int c = 0; c < 3; ++c)
        aw[c] = *reinterpret_cast<const bf16x8*>(wq + (size_t)(wave*48 + c*16 + r)*192 + ks*32 + 8*g);
      #pragma unroll
      for (int tt = 0; tt < 4; ++tt){
        const bf16x8 bx = *reinterpret_cast<const bf16x8*>(&XA[tt*16 + r][ks*32 + 8*g]);
        #pragma unroll
        for (int c = 0; c < 3; ++c)
          qa[c][tt] = __builtin_amdgcn_mfma_f32_16x16x32_bf16(aw[c], bx, qa[c][tt], 0, 0, 0);
      }
    }
    const float S = 0.17677669529663687f;
    #pragma unroll
    for (int c = 0; c < 3; ++c){
      const int ch0 = wave*48 + c*16 + 4*g;
      const float4 bi = *reinterpret_cast<const float4*>(qb + ch0);
      const size_t ub = ((size_t)(wi*6 + (ch0 >> 5))*64)*32 + (ch0 & 31);
      #pragma unroll
      for (int tt = 0; tt < 4; ++tt){
        uint2 t;
        t.x = pk2((qa[c][tt][0] + bi.x)*S, (qa[c][tt][1] + bi.y)*S);
        t.y = pk2((qa[c][tt][2] + bi.z)*S, (qa[c][tt][3] + bi.w)*S);
        *reinterpret_cast<uint2*>(qG + ub + (size_t)(tt*16 + r)*32) = t;
      }
    }
  }

  // ---- k (swapped MFMA) -> kG[u][tok][32] ----
  {
    f32x4 ka[3][4];
    #pragma unroll
    for (int c = 0; c < 3; ++c)
      #pragma unroll
      for (int tt = 0; tt < 4; ++tt) ka[c][tt] = z4;
    #pragma unroll
    for (int ks = 0; ks < 6; ++ks){
      bf16x8 aw[3];
      #pragma unroll
      for (int c = 0; c < 3; ++c)
        aw[c] = *reinterpret_cast<const bf16x8*>(wq + (size_t)(192 + wave*48 + c*16 + r)*192 + ks*32 + 8*g);
      #pragma unroll
      for (int tt = 0; tt < 4; ++tt){
        const bf16x8 bx = *reinterpret_cast<const bf16x8*>(&XA[tt*16 + r][ks*32 + 8*g]);
        #pragma unroll
        for (int c = 0; c < 3; ++c)
          ka[c][tt] = __builtin_amdgcn_mfma_f32_16x16x32_bf16(aw[c], bx, ka[c][tt], 0, 0, 0);
      }
    }
    #pragma unroll
    for (int c = 0; c < 3; ++c){
      const int ch0 = wave*48 + c*16 + 4*g;
      const float4 bi = *reinterpret_cast<const float4*>(qb + 192 + ch0);
      const size_t ub = ((size_t)(wi*6 + (ch0 >> 5))*64)*32 + (ch0 & 31);
      #pragma unroll
      for (int tt = 0; tt < 4; ++tt){
        uint2 t;
        t.x = pk2(ka[c][tt][0] + bi.x, ka[c][tt][1] + bi.y);
        t.y = pk2(ka[c][tt][2] + bi.z, ka[c][tt][3] + bi.w);
        *reinterpret_cast<uint2*>(kG + ub + (size_t)(tt*16 + r)*32) = t;
      }
    }
  }
}

// ---------------- B: attention, 1 wave per (window,head) unit ----------------
__global__ __launch_bounds__(256, 4) void attn_kernel(const u16* __restrict__ qG,
    const u16* __restrict__ kG, const u16* __restrict__ vG,
    const float* __restrict__ biasC, u16* __restrict__ AOG)
{
  __shared__ u16 Psh[4][2][16][72];   // per-wave, double-buffered P
  const int tid = threadIdx.x;
  const int wave = tid >> 6, lane = tid & 63;
  const int g = lane >> 4, r = lane & 15;
  const int unit = blockIdx.x * 4 + wave;     // 3072*4 = 12288
  const int wi = unit / 6, h = unit % 6;
  const int wy = (wi >> 3) & 7, wx = wi & 7;
  const int cls = ((wy == 7) ? 2 : 0) + ((wx == 7) ? 1 : 0);
  const float* bC = biasC + ((size_t)(cls*6 + h)*64)*72;
  const u16* qp = qG + (size_t)unit*2048;
  const f32x4 z4 = {0.f, 0.f, 0.f, 0.f};

  // unit-wide fragments, loaded once
  bf16x8 ak[4];
  #pragma unroll
  for (int mt = 0; mt < 4; ++mt)
    ak[mt] = *reinterpret_cast<const bf16x8*>(kG + ((size_t)unit*64 + mt*16 + r)*32 + 8*g);
  bf16x8 av[2][2];
  #pragma unroll
  for (int nt = 0; nt < 2; ++nt)
    #pragma unroll
    for (int k2 = 0; k2 < 2; ++k2)
      av[nt][k2] = *reinterpret_cast<const bf16x8*>(vG + ((size_t)unit*32 + nt*16 + r)*64 + k2*32 + 8*g);

  #pragma unroll 2
  for (int mt2 = 0; mt2 < 4; ++mt2){
    const int i_r = mt2*16 + r;
    const bf16x8 aq = *reinterpret_cast<const bf16x8*>(qp + (size_t)i_r*32 + 8*g);
    float4 bf[4];
    #pragma unroll
    for (int mt = 0; mt < 4; ++mt)
      bf[mt] = *reinterpret_cast<const float4*>(bC + (size_t)i_r*72 + mt*16 + 4*g);
    f32x4 s[4];
    #pragma unroll
    for (int mt = 0; mt < 4; ++mt)
      s[mt] = __builtin_amdgcn_mfma_f32_16x16x32_bf16(ak[mt], aq, z4, 0, 0, 0);
    float mx = -1e30f;
    #pragma unroll
    for (int mt = 0; mt < 4; ++mt)
      #pragma unroll
      for (int jj = 0; jj < 4; ++jj){
        const float t = s[mt][jj] + bf[mt][jj];
        s[mt][jj] = t;
        mx = fmaxf(mx, t);
      }
    mx = fmaxf(mx, __shfl_xor(mx, 16));
    mx = fmaxf(mx, __shfl_xor(mx, 32));
    float sum = 0.f;
    #pragma unroll
    for (int mt = 0; mt < 4; ++mt)
      #pragma unroll
      for (int jj = 0; jj < 4; ++jj){
        const float p = __expf(s[mt][jj] - mx);
        s[mt][jj] = p;
        sum += p;
      }
    sum += __shfl_xor(sum, 16);
    sum += __shfl_xor(sum, 32);
    const float rs = 1.0f / sum;
    #pragma unroll
    for (int mt = 0; mt < 4; ++mt){
      uint2 pw;
      pw.x = pk2(s[mt][0]*rs, s[mt][1]*rs);
      pw.y = pk2(s[mt][2]*rs, s[mt][3]*rs);
      *reinterpret_cast<uint2*>(&Psh[wave][mt2 & 1][r][16*mt + 4*g]) = pw;
    }
    f32x4 o[2] = {z4, z4};
    #pragma unroll
    for (int k2 = 0; k2 < 2; ++k2){
      const bf16x8 bp = *reinterpret_cast<const bf16x8*>(&Psh[wave][mt2 & 1][r][32*k2 + 8*g]);
      #pragma unroll
      for (int nt = 0; nt < 2; ++nt)
        o[nt] = __builtin_amdgcn_mfma_f32_16x16x32_bf16(av[nt][k2], bp, o[nt], 0, 0, 0);
    }
    #pragma unroll
    for (int nt = 0; nt < 2; ++nt){
      uint2 t;
      t.x = pk2(o[nt][0], o[nt][1]);
      t.y = pk2(o[nt][2], o[nt][3]);
      *reinterpret_cast<uint2*>(AOG + ((size_t)(wi*64 + i_r))*192 + h*32 + nt*16 + 4*g) = t;
    }
  }
}

// ---------------- C: proj GEMM + window-reverse + roll-back ----------------
__global__ __launch_bounds__(256, 4) void proj_kernel(const u16* __restrict__ AOG,
    const u16* __restrict__ wp, const float* __restrict__ pb, float* __restrict__ out)
{
  const int wi = blockIdx.x;
  const int bb = wi >> 6, wy = (wi >> 3) & 7, wx = wi & 7;
  const int tid = threadIdx.x;
  const int wave = tid >> 6, lane = tid & 63;
  const int g = lane >> 4, r = lane & 15;
  const f32x4 z4 = {0.f, 0.f, 0.f, 0.f};

  f32x4 pacc[4][3];
  #pragma unroll
  for (int mt = 0; mt < 4; ++mt){ pacc[mt][0] = z4; pacc[mt][1] = z4; pacc[mt][2] = z4; }
  #pragma unroll
  for (int ks = 0; ks < 6; ++ks){
    bf16x8 a2[4];
    #pragma unroll
    for (int mt = 0; mt < 4; ++mt)
      a2[mt] = *reinterpret_cast<const bf16x8*>(AOG + ((size_t)(wi*64 + mt*16 + r))*192 + ks*32 + 8*g);
    #pragma unroll
    for (int nt = 0; nt < 3; ++nt){
      const bf16x8 bw = *reinterpret_cast<const bf16x8*>(wp + (size_t)(wave*48 + nt*16 + r)*192 + ks*32 + 8*g);
      #pragma unroll
      for (int mt = 0; mt < 4; ++mt)
        pacc[mt][nt] = __builtin_amdgcn_mfma_f32_16x16x32_bf16(a2[mt], bw, pacc[mt][nt], 0, 0, 0);
    }
  }
  #pragma unroll
  for (int nt = 0; nt < 3; ++nt){
    const int n = wave*48 + nt*16 + r;
    const float bias = pb[n];
    #pragma unroll
    for (int mt = 0; mt < 4; ++mt)
      #pragma unroll
      for (int jj = 0; jj < 4; ++jj){
        const int tok = mt*16 + 4*g + jj;
        if (tok < 49){
          const int ty = tok/7, tx = tok%7;
          int dh = wy*7 + ty + 3; if (dh >= 56) dh -= 56;
          int dw = wx*7 + tx + 3; if (dw >= 56) dw -= 56;
          out[(size_t)((bb*56 + dh)*56 + dw)*192 + n] = pacc[mt][nt][jj] + bias;
        }
      }
  }
}

extern "C" void kernel_launch(void* const* d_in, const int* in_sizes, int n_in,
                              void* d_out, int out_size, void* d_ws, size_t ws_size,
                              hipStream_t stream) {
  const float* x     = (const float*)d_in[0];
  const float* rpb   = (const float*)d_in[1];
  const float* qkvw  = (const float*)d_in[2];
  const float* qkvb  = (const float*)d_in[3];
  const float* projw = (const float*)d_in[4];
  const float* projb = (const float*)d_in[5];
  float* out = (float*)d_out;

  char* ws = (char*)d_ws;
  u16*   wq    = (u16*)(ws);                                   // bf16 [576][192]
  u16*   wpj   = (u16*)(ws + 221184);                          // bf16 [192][192]
  float* biasC = (float*)(ws + 221184 + 73728);                // f32  [4][6][64][72]
  u16*   qG    = (u16*)(ws + 737280);                          // bf16 [12288][64][32]
  u16*   kG    = (u16*)(ws + 737280 + 1ll*50331648);           // bf16 [12288][64][32]
  u16*   vG    = (u16*)(ws + 737280 + 2ll*50331648);           // bf16 [12288][32][64]
  u16*   AOG   = (u16*)(ws + 737280 + 3ll*50331648);           // bf16 [2048][64][192]

  prep_kernel<<<432, 256, 0, stream>>>(qkvw, projw, rpb, wq, wpj, biasC);
  qkv_kernel <<<2048, 256, 0, stream>>>(x, wq, qkvb, qG, kG, vG);
  attn_kernel<<<3072, 256, 0, stream>>>(qG, kG, vG, biasC, AOG);
  proj_kernel<<<2048, 256, 0, stream>>>(AOG, wpj, projb, out);
}

// Round 9
// 155.634 us; speedup vs baseline: 1.1956x; 1.1956x over previous
//
#include <hip/hip_runtime.h>

typedef unsigned short u16;
typedef unsigned int   u32;
typedef __bf16 bf16x8 __attribute__((ext_vector_type(8)));
typedef float  f32x4  __attribute__((ext_vector_type(4)));

// Geometry (fixed): b=32, h=w=56, C=192, NH=6, hd=32, WS=7, shift=3
// 2048 windows, 49 tokens (padded to 64).
// V9: A: gather+QKV (launch_bounds(256,3), hoisted gather loads)
//     B: attn+proj merged, block=window, 384 thr, wave=head, AO in LDS.

__device__ __forceinline__ u16 f2b(float f){
  return __builtin_bit_cast(u16, (__bf16)f);
}
__device__ __forceinline__ u32 pk2(float a, float b){
  return (u32)f2b(a) | ((u32)f2b(b) << 16);
}

__device__ __forceinline__ int coords_fn(int t){ return (t/7)*13 + (t%7); }
__device__ __forceinline__ int code_fn(int t, int wy, int wx){
  const int ty = t/7, tx = t%7;
  const int hp = wy*7 + ty, wp = wx*7 + tx;
  const int rh = (hp < 49) ? 0 : ((hp < 53) ? 1 : 2);
  const int rw = (wp < 49) ? 0 : ((wp < 53) ? 1 : 2);
  return rh*3 + rw;
}

// prep: weights fp32->bf16; biasC[cls][h][i][j] = rpb + (-100 shift mask) + (-1e30 j>=49)
__global__ __launch_bounds__(256) void prep_kernel(const float* __restrict__ qkvw,
                                                   const float* __restrict__ projw,
                                                   const float* __restrict__ rpb,
                                                   u16* __restrict__ wq, u16* __restrict__ wp,
                                                   float* __restrict__ biasC){
  const int i = blockIdx.x * 256 + threadIdx.x;   // 432*256 = 110592
  if (i < 576*192) wq[i] = f2b(qkvw[i]);
  if (i < 192*192) wp[i] = f2b(projw[i]);
  {
    const int cls = i / 27648, rem = i % 27648;
    const int h = rem / 4608, rem2 = rem % 4608;
    const int ii = rem2 / 72, j = rem2 % 72;
    const int wyR = (cls & 2) ? 7 : 0, wxR = (cls & 1) ? 7 : 0;
    float v = -1e30f;
    if (j < 49){
      const int icl = (ii > 48) ? 48 : ii;
      v = rpb[(coords_fn(icl) + coords_fn(48 - j))*6 + h];
      if (code_fn(icl, wyR, wxR) != code_fn(j, wyR, wxR)) v -= 100.0f;
    }
    biasC[i] = v;
  }
}

// ---------------- A: roll + gather + QKV GEMM -> qG/kG/vG ----------------
__global__ __launch_bounds__(256, 3) void qkv_kernel(const float* __restrict__ x,
    const u16* __restrict__ wq, const float* __restrict__ qb,
    u16* __restrict__ qG, u16* __restrict__ kG, u16* __restrict__ vG)
{
  __shared__ u16 XA[64][200];
  const int wi = blockIdx.x;
  const int bb = wi >> 6, wy = (wi >> 3) & 7, wx = wi & 7;
  const int tid = threadIdx.x;
  const int wave = tid >> 6, lane = tid & 63;
  const int g = lane >> 4, r = lane & 15;
  const f32x4 z4 = {0.f, 0.f, 0.f, 0.f};

  // gather: 6 chunks/thread of 16 bf16 (2 float4 loads each), all loads hoisted
  {
    float4 gv[6][2];
    int grow[6], gc8[6];
    #pragma unroll
    for (int i2 = 0; i2 < 6; ++i2){
      const int idx = i2*256 + tid;          // < 1536 = 64*24
      const int row = idx / 24, c8 = (idx % 24) * 8;
      grow[i2] = row; gc8[i2] = c8;
      if (row < 49){
        const int ty = row / 7, tx = row % 7;
        int sh = wy*7 + ty + 3; if (sh >= 56) sh -= 56;
        int sw = wx*7 + tx + 3; if (sw >= 56) sw -= 56;
        const float* src = x + (size_t)(((bb*56 + sh)*56 + sw))*192 + c8;
        gv[i2][0] = *reinterpret_cast<const float4*>(src);
        gv[i2][1] = *reinterpret_cast<const float4*>(src + 4);
      } else {
        gv[i2][0] = make_float4(0.f,0.f,0.f,0.f);
        gv[i2][1] = make_float4(0.f,0.f,0.f,0.f);
      }
    }
    #pragma unroll
    for (int i2 = 0; i2 < 6; ++i2){
      uint4 w;
      w.x = pk2(gv[i2][0].x, gv[i2][0].y);
      w.y = pk2(gv[i2][0].z, gv[i2][0].w);
      w.z = pk2(gv[i2][1].x, gv[i2][1].y);
      w.w = pk2(gv[i2][1].z, gv[i2][1].w);
      *reinterpret_cast<uint4*>(&XA[grow[i2]][gc8[i2]]) = w;
    }
  }
  __syncthreads();   // only barrier

  // ---- v (normal MFMA) -> vG[u][d][tok] ----
  {
    f32x4 va[4][3];
    #pragma unroll
    for (int mt = 0; mt < 4; ++mt)
      #pragma unroll
      for (int nt = 0; nt < 3; ++nt) va[mt][nt] = z4;
    #pragma unroll
    for (int ks = 0; ks < 6; ++ks){
      bf16x8 ax[4];
      #pragma unroll
      for (int mt = 0; mt < 4; ++mt)
        ax[mt] = *reinterpret_cast<const bf16x8*>(&XA[mt*16 + r][ks*32 + 8*g]);
      #pragma unroll
      for (int nt = 0; nt < 3; ++nt){
        const bf16x8 bw = *reinterpret_cast<const bf16x8*>(wq + (size_t)(384 + wave*48 + nt*16 + r)*192 + ks*32 + 8*g);
        #pragma unroll
        for (int mt = 0; mt < 4; ++mt)
          va[mt][nt] = __builtin_amdgcn_mfma_f32_16x16x32_bf16(ax[mt], bw, va[mt][nt], 0, 0, 0);
      }
    }
    #pragma unroll
    for (int nt = 0; nt < 3; ++nt){
      const int ch = wave*48 + nt*16 + r;
      const float bv = qb[384 + ch];
      const size_t ubase = ((size_t)(wi*6 + (ch >> 5))*32 + (ch & 31))*64;
      #pragma unroll
      for (int mt = 0; mt < 4; ++mt){
        uint2 t;
        t.x = pk2(va[mt][nt][0] + bv, va[mt][nt][1] + bv);
        t.y = pk2(va[mt][nt][2] + bv, va[mt][nt][3] + bv);
        *reinterpret_cast<uint2*>(vG + ubase + mt*16 + 4*g) = t;
      }
    }
  }

  // ---- q (swapped MFMA) -> qG[u][tok][32], scaled ----
  {
    f32x4 qa[3][4];
    #pragma unroll
    for (int c = 0; c < 3; ++c)
      #pragma unroll
      for (int tt = 0; tt < 4; ++tt) qa[c][tt] = z4;
    #pragma unroll
    for (int ks = 0; ks < 6; ++ks){
      bf16x8 aw[3];
      #pragma unroll
      for (int c = 0; c < 3; ++c)
        aw[c] = *reinterpret_cast<const bf16x8*>(wq + (size_t)(wave*48 + c*16 + r)*192 + ks*32 + 8*g);
      #pragma unroll
      for (int tt = 0; tt < 4; ++tt){
        const bf16x8 bx = *reinterpret_cast<const bf16x8*>(&XA[tt*16 + r][ks*32 + 8*g]);
        #pragma unroll
        for (int c = 0; c < 3; ++c)
          qa[c][tt] = __builtin_amdgcn_mfma_f32_16x16x32_bf16(aw[c], bx, qa[c][tt], 0, 0, 0);
      }
    }
    const float S = 0.17677669529663687f;
    #pragma unroll
    for (int c = 0; c < 3; ++c){
      const int ch0 = wave*48 + c*16 + 4*g;
      const float4 bi = *reinterpret_cast<const float4*>(qb + ch0);
      const size_t ub = ((size_t)(wi*6 + (ch0 >> 5))*64)*32 + (ch0 & 31);
      #pragma unroll
      for (int tt = 0; tt < 4; ++tt){
        uint2 t;
        t.x = pk2((qa[c][tt][0] + bi.x)*S, (qa[c][tt][1] + bi.y)*S);
        t.y = pk2((qa[c][tt][2] + bi.z)*S, (qa[c][tt][3] + bi.w)*S);
        *reinterpret_cast<uint2*>(qG + ub + (size_t)(tt*16 + r)*32) = t;
      }
    }
  }

  // ---- k (swapped MFMA) -> kG[u][tok][32] ----
  {
    f32x4 ka[3][4];
    #pragma unroll
    for (int c = 0; c < 3; ++c)
      #pragma unroll
      for (int tt = 0; tt < 4; ++tt) ka[c][tt] = z4;
    #pragma unroll
    for (int ks = 0; ks < 6; ++ks){
      bf16x8 aw[3];
      #pragma unroll
      for (int c = 0; c < 3; ++c)
        aw[c] = *reinterpret_cast<const bf16x8*>(wq + (size_t)(192 + wave*48 + c*16 + r)*192 + ks*32 + 8*g);
      #pragma unroll
      for (int tt = 0; tt < 4; ++tt){
        const bf16x8 bx = *reinterpret_cast<const bf16x8*>(&XA[tt*16 + r][ks*32 + 8*g]);
        #pragma unroll
        for (int c = 0; c < 3; ++c)
          ka[c][tt] = __builtin_amdgcn_mfma_f32_16x16x32_bf16(aw[c], bx, ka[c][tt], 0, 0, 0);
      }
    }
    #pragma unroll
    for (int c = 0; c < 3; ++c){
      const int ch0 = wave*48 + c*16 + 4*g;
      const float4 bi = *reinterpret_cast<const float4*>(qb + 192 + ch0);
      const size_t ub = ((size_t)(wi*6 + (ch0 >> 5))*64)*32 + (ch0 & 31);
      #pragma unroll
      for (int tt = 0; tt < 4; ++tt){
        uint2 t;
        t.x = pk2(ka[c][tt][0] + bi.x, ka[c][tt][1] + bi.y);
        t.y = pk2(ka[c][tt][2] + bi.z, ka[c][tt][3] + bi.w);
        *reinterpret_cast<uint2*>(kG + ub + (size_t)(tt*16 + r)*32) = t;
      }
    }
  }
}

// ---------------- B: attention (wave=head) + proj, block = 1 window ----------------
__global__ __launch_bounds__(384, 4) void attnproj_kernel(const u16* __restrict__ qG,
    const u16* __restrict__ kG, const u16* __restrict__ vG,
    const float* __restrict__ biasC, const u16* __restrict__ wp,
    const float* __restrict__ pb, float* __restrict__ out)
{
  __shared__ u16 AO[64][200];        // attention output [tok][192]
  __shared__ u16 Psh[6][2][16][72];  // per-wave double-buffered P
  const int wi = blockIdx.x;
  const int bb = wi >> 6, wy = (wi >> 3) & 7, wx = wi & 7;
  const int tid = threadIdx.x;
  const int h = tid / 64;            // wave = head
  const int lane = tid & 63;
  const int g = lane >> 4, r = lane & 15;
  const int unit = wi*6 + h;
  const int cls = ((wy == 7) ? 2 : 0) + ((wx == 7) ? 1 : 0);
  const float* bC = biasC + ((size_t)(cls*6 + h)*64)*72;
  const u16* qp = qG + (size_t)unit*2048;
  const f32x4 z4 = {0.f, 0.f, 0.f, 0.f};

  // unit-wide fragments, loaded once
  bf16x8 ak[4];
  #pragma unroll
  for (int mt = 0; mt < 4; ++mt)
    ak[mt] = *reinterpret_cast<const bf16x8*>(kG + ((size_t)unit*64 + mt*16 + r)*32 + 8*g);
  bf16x8 av[2][2];
  #pragma unroll
  for (int nt = 0; nt < 2; ++nt)
    #pragma unroll
    for (int k2 = 0; k2 < 2; ++k2)
      av[nt][k2] = *reinterpret_cast<const bf16x8*>(vG + ((size_t)unit*32 + nt*16 + r)*64 + k2*32 + 8*g);

  #pragma unroll 2
  for (int mt2 = 0; mt2 < 4; ++mt2){
    const int i_r = mt2*16 + r;
    const bf16x8 aq = *reinterpret_cast<const bf16x8*>(qp + (size_t)i_r*32 + 8*g);
    float4 bf[4];
    #pragma unroll
    for (int mt = 0; mt < 4; ++mt)
      bf[mt] = *reinterpret_cast<const float4*>(bC + (size_t)i_r*72 + mt*16 + 4*g);
    f32x4 s[4];
    #pragma unroll
    for (int mt = 0; mt < 4; ++mt)
      s[mt] = __builtin_amdgcn_mfma_f32_16x16x32_bf16(ak[mt], aq, z4, 0, 0, 0);
    float mx = -1e30f;
    #pragma unroll
    for (int mt = 0; mt < 4; ++mt)
      #pragma unroll
      for (int jj = 0; jj < 4; ++jj){
        const float t = s[mt][jj] + bf[mt][jj];
        s[mt][jj] = t;
        mx = fmaxf(mx, t);
      }
    mx = fmaxf(mx, __shfl_xor(mx, 16));
    mx = fmaxf(mx, __shfl_xor(mx, 32));
    float sum = 0.f;
    #pragma unroll
    for (int mt = 0; mt < 4; ++mt)
      #pragma unroll
      for (int jj = 0; jj < 4; ++jj){
        const float p = __expf(s[mt][jj] - mx);
        s[mt][jj] = p;
        sum += p;
      }
    sum += __shfl_xor(sum, 16);
    sum += __shfl_xor(sum, 32);
    const float rs = 1.0f / sum;
    #pragma unroll
    for (int mt = 0; mt < 4; ++mt){
      uint2 pw;
      pw.x = pk2(s[mt][0]*rs, s[mt][1]*rs);
      pw.y = pk2(s[mt][2]*rs, s[mt][3]*rs);
      *reinterpret_cast<uint2*>(&Psh[h][mt2 & 1][r][16*mt + 4*g]) = pw;
    }
    f32x4 o[2] = {z4, z4};
    #pragma unroll
    for (int k2 = 0; k2 < 2; ++k2){
      const bf16x8 bp = *reinterpret_cast<const bf16x8*>(&Psh[h][mt2 & 1][r][32*k2 + 8*g]);
      #pragma unroll
      for (int nt = 0; nt < 2; ++nt)
        o[nt] = __builtin_amdgcn_mfma_f32_16x16x32_bf16(av[nt][k2], bp, o[nt], 0, 0, 0);
    }
    #pragma unroll
    for (int nt = 0; nt < 2; ++nt){
      uint2 t;
      t.x = pk2(o[nt][0], o[nt][1]);
      t.y = pk2(o[nt][2], o[nt][3]);
      *reinterpret_cast<uint2*>(&AO[i_r][h*32 + nt*16 + 4*g]) = t;
    }
  }
  __syncthreads();

  // ---- proj: 6 waves x 32 cols; A-frags from AO (LDS) ----
  {
    f32x4 pacc[4][2];
    #pragma unroll
    for (int mt = 0; mt < 4; ++mt){ pacc[mt][0] = z4; pacc[mt][1] = z4; }
    #pragma unroll
    for (int ks = 0; ks < 6; ++ks){
      bf16x8 a2[4];
      #pragma unroll
      for (int mt = 0; mt < 4; ++mt)
        a2[mt] = *reinterpret_cast<const bf16x8*>(&AO[mt*16 + r][ks*32 + 8*g]);
      #pragma unroll
      for (int nt = 0; nt < 2; ++nt){
        const bf16x8 bw = *reinterpret_cast<const bf16x8*>(wp + (size_t)(h*32 + nt*16 + r)*192 + ks*32 + 8*g);
        #pragma unroll
        for (int mt = 0; mt < 4; ++mt)
          pacc[mt][nt] = __builtin_amdgcn_mfma_f32_16x16x32_bf16(a2[mt], bw, pacc[mt][nt], 0, 0, 0);
      }
    }
    #pragma unroll
    for (int nt = 0; nt < 2; ++nt){
      const int n = h*32 + nt*16 + r;
      const float bias = pb[n];
      #pragma unroll
      for (int mt = 0; mt < 4; ++mt)
        #pragma unroll
        for (int jj = 0; jj < 4; ++jj){
          const int tok = mt*16 + 4*g + jj;
          if (tok < 49){
            const int ty = tok/7, tx = tok%7;
            int dh = wy*7 + ty + 3; if (dh >= 56) dh -= 56;
            int dw = wx*7 + tx + 3; if (dw >= 56) dw -= 56;
            out[(size_t)((bb*56 + dh)*56 + dw)*192 + n] = pacc[mt][nt][jj] + bias;
          }
        }
    }
  }
}

extern "C" void kernel_launch(void* const* d_in, const int* in_sizes, int n_in,
                              void* d_out, int out_size, void* d_ws, size_t ws_size,
                              hipStream_t stream) {
  const float* x     = (const float*)d_in[0];
  const float* rpb   = (const float*)d_in[1];
  const float* qkvw  = (const float*)d_in[2];
  const float* qkvb  = (const float*)d_in[3];
  const float* projw = (const float*)d_in[4];
  const float* projb = (const float*)d_in[5];
  float* out = (float*)d_out;

  char* ws = (char*)d_ws;
  u16*   wq    = (u16*)(ws);                                   // bf16 [576][192]
  u16*   wpj   = (u16*)(ws + 221184);                          // bf16 [192][192]
  float* biasC = (float*)(ws + 221184 + 73728);                // f32  [4][6][64][72]
  u16*   qG    = (u16*)(ws + 737280);                          // bf16 [12288][64][32]
  u16*   kG    = (u16*)(ws + 737280 + 1ll*50331648);           // bf16 [12288][64][32]
  u16*   vG    = (u16*)(ws + 737280 + 2ll*50331648);           // bf16 [12288][32][64]

  prep_kernel    <<<432, 256, 0, stream>>>(qkvw, projw, rpb, wq, wpj, biasC);
  qkv_kernel     <<<2048, 256, 0, stream>>>(x, wq, qkvb, qG, kG, vG);
  attnproj_kernel<<<2048, 384, 0, stream>>>(qG, kG, vG, biasC, wpj, projb, out);
}

// Round 10
// 138.660 us; speedup vs baseline: 1.3420x; 1.1224x over previous
//
#include <hip/hip_runtime.h>

typedef unsigned short u16;
typedef unsigned int   u32;
typedef __bf16 bf16x8 __attribute__((ext_vector_type(8)));
typedef float  f32x4  __attribute__((ext_vector_type(4)));

// Geometry (fixed): b=32, h=w=56, C=192, NH=6, hd=32, WS=7, shift=3
// 2048 windows, 49 tokens (padded to 64).
// V10: qkv = 2 windows/block (M=128), wave owns 128 rows x 48 cols/segment:
//      24 MFMA per 3 weight loads, launch_bounds(256,2) for reg headroom.
//      attnproj unchanged from R9 (measured ~45us, near BW roofline).

__device__ __forceinline__ u16 f2b(float f){
  return __builtin_bit_cast(u16, (__bf16)f);
}
__device__ __forceinline__ u32 pk2(float a, float b){
  return (u32)f2b(a) | ((u32)f2b(b) << 16);
}

__device__ __forceinline__ int coords_fn(int t){ return (t/7)*13 + (t%7); }
__device__ __forceinline__ int code_fn(int t, int wy, int wx){
  const int ty = t/7, tx = t%7;
  const int hp = wy*7 + ty, wp = wx*7 + tx;
  const int rh = (hp < 49) ? 0 : ((hp < 53) ? 1 : 2);
  const int rw = (wp < 49) ? 0 : ((wp < 53) ? 1 : 2);
  return rh*3 + rw;
}

// prep: weights fp32->bf16; biasC[cls][h][i][j] = rpb + (-100 shift mask) + (-1e30 j>=49)
__global__ __launch_bounds__(256) void prep_kernel(const float* __restrict__ qkvw,
                                                   const float* __restrict__ projw,
                                                   const float* __restrict__ rpb,
                                                   u16* __restrict__ wq, u16* __restrict__ wp,
                                                   float* __restrict__ biasC){
  const int i = blockIdx.x * 256 + threadIdx.x;   // 432*256 = 110592
  if (i < 576*192) wq[i] = f2b(qkvw[i]);
  if (i < 192*192) wp[i] = f2b(projw[i]);
  {
    const int cls = i / 27648, rem = i % 27648;
    const int h = rem / 4608, rem2 = rem % 4608;
    const int ii = rem2 / 72, j = rem2 % 72;
    const int wyR = (cls & 2) ? 7 : 0, wxR = (cls & 1) ? 7 : 0;
    float v = -1e30f;
    if (j < 49){
      const int icl = (ii > 48) ? 48 : ii;
      v = rpb[(coords_fn(icl) + coords_fn(48 - j))*6 + h];
      if (code_fn(icl, wyR, wxR) != code_fn(j, wyR, wxR)) v -= 100.0f;
    }
    biasC[i] = v;
  }
}

// ---------------- A: roll + gather + QKV GEMM (2 windows/block) ----------------
__global__ __launch_bounds__(256, 2) void qkv_kernel(const float* __restrict__ x,
    const u16* __restrict__ wq, const float* __restrict__ qb,
    u16* __restrict__ qG, u16* __restrict__ kG, u16* __restrict__ vG)
{
  __shared__ u16 XA[128][200];       // 2 windows x 64 tokens x 192ch
  const int wi0 = blockIdx.x * 2;    // windows wi0, wi0+1 (same bb, same wy)
  const int bb = wi0 >> 6, wy = (wi0 >> 3) & 7;
  const int tid = threadIdx.x;
  const int wave = tid >> 6, lane = tid & 63;
  const int g = lane >> 4, r = lane & 15;
  const f32x4 z4 = {0.f, 0.f, 0.f, 0.f};

  // gather: 2 halves x 6 chunks/thread of 16 bf16 (loads hoisted per half)
  #pragma unroll
  for (int half = 0; half < 2; ++half){
    float4 gv[6][2];
    int grow[6], gc8[6];
    #pragma unroll
    for (int i2 = 0; i2 < 6; ++i2){
      const int idx = half*1536 + i2*256 + tid;   // < 3072 = 128*24
      const int row = idx / 24, c8 = (idx % 24) * 8;
      grow[i2] = row; gc8[i2] = c8;
      const int rl = row & 63;
      const int wx = (wi0 + (row >> 6)) & 7;
      if (rl < 49){
        const int ty = rl / 7, tx = rl % 7;
        int sh = wy*7 + ty + 3; if (sh >= 56) sh -= 56;
        int sw = wx*7 + tx + 3; if (sw >= 56) sw -= 56;
        const float* src = x + (size_t)(((bb*56 + sh)*56 + sw))*192 + c8;
        gv[i2][0] = *reinterpret_cast<const float4*>(src);
        gv[i2][1] = *reinterpret_cast<const float4*>(src + 4);
      } else {
        gv[i2][0] = make_float4(0.f,0.f,0.f,0.f);
        gv[i2][1] = make_float4(0.f,0.f,0.f,0.f);
      }
    }
    #pragma unroll
    for (int i2 = 0; i2 < 6; ++i2){
      uint4 w;
      w.x = pk2(gv[i2][0].x, gv[i2][0].y);
      w.y = pk2(gv[i2][0].z, gv[i2][0].w);
      w.z = pk2(gv[i2][1].x, gv[i2][1].y);
      w.w = pk2(gv[i2][1].z, gv[i2][1].w);
      *reinterpret_cast<uint4*>(&XA[grow[i2]][gc8[i2]]) = w;
    }
  }
  __syncthreads();   // only barrier

  // ---- q segment (swapped MFMA): cols wave*48..+47 of q ----
  {
    f32x4 acc[8][3];
    #pragma unroll
    for (int mt = 0; mt < 8; ++mt)
      #pragma unroll
      for (int c = 0; c < 3; ++c) acc[mt][c] = z4;
    #pragma unroll
    for (int ks = 0; ks < 6; ++ks){
      bf16x8 aw[3];
      #pragma unroll
      for (int c = 0; c < 3; ++c)
        aw[c] = *reinterpret_cast<const bf16x8*>(wq + (size_t)(wave*48 + c*16 + r)*192 + ks*32 + 8*g);
      bf16x8 ax[8];
      #pragma unroll
      for (int mt = 0; mt < 8; ++mt)
        ax[mt] = *reinterpret_cast<const bf16x8*>(&XA[mt*16 + r][ks*32 + 8*g]);
      #pragma unroll
      for (int mt = 0; mt < 8; ++mt)
        #pragma unroll
        for (int c = 0; c < 3; ++c)
          acc[mt][c] = __builtin_amdgcn_mfma_f32_16x16x32_bf16(aw[c], ax[mt], acc[mt][c], 0, 0, 0);
    }
    const float S = 0.17677669529663687f;
    #pragma unroll
    for (int c = 0; c < 3; ++c){
      const int ch0 = wave*48 + c*16 + 4*g;
      const float4 bi = *reinterpret_cast<const float4*>(qb + ch0);
      #pragma unroll
      for (int mt = 0; mt < 8; ++mt){
        const int u = (wi0 + (mt >> 2))*6 + (ch0 >> 5);
        const int tok = (mt & 3)*16 + r;
        uint2 t;
        t.x = pk2((acc[mt][c][0] + bi.x)*S, (acc[mt][c][1] + bi.y)*S);
        t.y = pk2((acc[mt][c][2] + bi.z)*S, (acc[mt][c][3] + bi.w)*S);
        *reinterpret_cast<uint2*>(qG + ((size_t)u*64 + tok)*32 + (ch0 & 31)) = t;
      }
    }
  }

  // ---- k segment (swapped MFMA) ----
  {
    f32x4 acc[8][3];
    #pragma unroll
    for (int mt = 0; mt < 8; ++mt)
      #pragma unroll
      for (int c = 0; c < 3; ++c) acc[mt][c] = z4;
    #pragma unroll
    for (int ks = 0; ks < 6; ++ks){
      bf16x8 aw[3];
      #pragma unroll
      for (int c = 0; c < 3; ++c)
        aw[c] = *reinterpret_cast<const bf16x8*>(wq + (size_t)(192 + wave*48 + c*16 + r)*192 + ks*32 + 8*g);
      bf16x8 ax[8];
      #pragma unroll
      for (int mt = 0; mt < 8; ++mt)
        ax[mt] = *reinterpret_cast<const bf16x8*>(&XA[mt*16 + r][ks*32 + 8*g]);
      #pragma unroll
      for (int mt = 0; mt < 8; ++mt)
        #pragma unroll
        for (int c = 0; c < 3; ++c)
          acc[mt][c] = __builtin_amdgcn_mfma_f32_16x16x32_bf16(aw[c], ax[mt], acc[mt][c], 0, 0, 0);
    }
    #pragma unroll
    for (int c = 0; c < 3; ++c){
      const int ch0 = wave*48 + c*16 + 4*g;
      const float4 bi = *reinterpret_cast<const float4*>(qb + 192 + ch0);
      #pragma unroll
      for (int mt = 0; mt < 8; ++mt){
        const int u = (wi0 + (mt >> 2))*6 + (ch0 >> 5);
        const int tok = (mt & 3)*16 + r;
        uint2 t;
        t.x = pk2(acc[mt][c][0] + bi.x, acc[mt][c][1] + bi.y);
        t.y = pk2(acc[mt][c][2] + bi.z, acc[mt][c][3] + bi.w);
        *reinterpret_cast<uint2*>(kG + ((size_t)u*64 + tok)*32 + (ch0 & 31)) = t;
      }
    }
  }

  // ---- v segment (normal MFMA) -> vG[u][d][tok] ----
  {
    f32x4 acc[8][3];
    #pragma unroll
    for (int mt = 0; mt < 8; ++mt)
      #pragma unroll
      for (int c = 0; c < 3; ++c) acc[mt][c] = z4;
    #pragma unroll
    for (int ks = 0; ks < 6; ++ks){
      bf16x8 bw[3];
      #pragma unroll
      for (int c = 0; c < 3; ++c)
        bw[c] = *reinterpret_cast<const bf16x8*>(wq + (size_t)(384 + wave*48 + c*16 + r)*192 + ks*32 + 8*g);
      bf16x8 ax[8];
      #pragma unroll
      for (int mt = 0; mt < 8; ++mt)
        ax[mt] = *reinterpret_cast<const bf16x8*>(&XA[mt*16 + r][ks*32 + 8*g]);
      #pragma unroll
      for (int mt = 0; mt < 8; ++mt)
        #pragma unroll
        for (int c = 0; c < 3; ++c)
          acc[mt][c] = __builtin_amdgcn_mfma_f32_16x16x32_bf16(ax[mt], bw[c], acc[mt][c], 0, 0, 0);
    }
    #pragma unroll
    for (int c = 0; c < 3; ++c){
      const int ch = wave*48 + c*16 + r;
      const float bv = qb[384 + ch];
      #pragma unroll
      for (int mt = 0; mt < 8; ++mt){
        const int u = (wi0 + (mt >> 2))*6 + (ch >> 5);
        const int d = ch & 31;
        uint2 t;
        t.x = pk2(acc[mt][c][0] + bv, acc[mt][c][1] + bv);
        t.y = pk2(acc[mt][c][2] + bv, acc[mt][c][3] + bv);
        *reinterpret_cast<uint2*>(vG + ((size_t)u*32 + d)*64 + (mt & 3)*16 + 4*g) = t;
      }
    }
  }
}

// ---------------- B: attention (wave=head) + proj, block = 1 window ----------------
__global__ __launch_bounds__(384, 4) void attnproj_kernel(const u16* __restrict__ qG,
    const u16* __restrict__ kG, const u16* __restrict__ vG,
    const float* __restrict__ biasC, const u16* __restrict__ wp,
    const float* __restrict__ pb, float* __restrict__ out)
{
  __shared__ u16 AO[64][200];        // attention output [tok][192]
  __shared__ u16 Psh[6][2][16][72];  // per-wave double-buffered P
  const int wi = blockIdx.x;
  const int bb = wi >> 6, wy = (wi >> 3) & 7, wx = wi & 7;
  const int tid = threadIdx.x;
  const int h = tid / 64;            // wave = head
  const int lane = tid & 63;
  const int g = lane >> 4, r = lane & 15;
  const int unit = wi*6 + h;
  const int cls = ((wy == 7) ? 2 : 0) + ((wx == 7) ? 1 : 0);
  const float* bC = biasC + ((size_t)(cls*6 + h)*64)*72;
  const u16* qp = qG + (size_t)unit*2048;
  const f32x4 z4 = {0.f, 0.f, 0.f, 0.f};

  // unit-wide fragments, loaded once
  bf16x8 ak[4];
  #pragma unroll
  for (int mt = 0; mt < 4; ++mt)
    ak[mt] = *reinterpret_cast<const bf16x8*>(kG + ((size_t)unit*64 + mt*16 + r)*32 + 8*g);
  bf16x8 av[2][2];
  #pragma unroll
  for (int nt = 0; nt < 2; ++nt)
    #pragma unroll
    for (int k2 = 0; k2 < 2; ++k2)
      av[nt][k2] = *reinterpret_cast<const bf16x8*>(vG + ((size_t)unit*32 + nt*16 + r)*64 + k2*32 + 8*g);

  #pragma unroll 2
  for (int mt2 = 0; mt2 < 4; ++mt2){
    const int i_r = mt2*16 + r;
    const bf16x8 aq = *reinterpret_cast<const bf16x8*>(qp + (size_t)i_r*32 + 8*g);
    float4 bf[4];
    #pragma unroll
    for (int mt = 0; mt < 4; ++mt)
      bf[mt] = *reinterpret_cast<const float4*>(bC + (size_t)i_r*72 + mt*16 + 4*g);
    f32x4 s[4];
    #pragma unroll
    for (int mt = 0; mt < 4; ++mt)
      s[mt] = __builtin_amdgcn_mfma_f32_16x16x32_bf16(ak[mt], aq, z4, 0, 0, 0);
    float mx = -1e30f;
    #pragma unroll
    for (int mt = 0; mt < 4; ++mt)
      #pragma unroll
      for (int jj = 0; jj < 4; ++jj){
        const float t = s[mt][jj] + bf[mt][jj];
        s[mt][jj] = t;
        mx = fmaxf(mx, t);
      }
    mx = fmaxf(mx, __shfl_xor(mx, 16));
    mx = fmaxf(mx, __shfl_xor(mx, 32));
    float sum = 0.f;
    #pragma unroll
    for (int mt = 0; mt < 4; ++mt)
      #pragma unroll
      for (int jj = 0; jj < 4; ++jj){
        const float p = __expf(s[mt][jj] - mx);
        s[mt][jj] = p;
        sum += p;
      }
    sum += __shfl_xor(sum, 16);
    sum += __shfl_xor(sum, 32);
    const float rs = 1.0f / sum;
    #pragma unroll
    for (int mt = 0; mt < 4; ++mt){
      uint2 pw;
      pw.x = pk2(s[mt][0]*rs, s[mt][1]*rs);
      pw.y = pk2(s[mt][2]*rs, s[mt][3]*rs);
      *reinterpret_cast<uint2*>(&Psh[h][mt2 & 1][r][16*mt + 4*g]) = pw;
    }
    f32x4 o[2] = {z4, z4};
    #pragma unroll
    for (int k2 = 0; k2 < 2; ++k2){
      const bf16x8 bp = *reinterpret_cast<const bf16x8*>(&Psh[h][mt2 & 1][r][32*k2 + 8*g]);
      #pragma unroll
      for (int nt = 0; nt < 2; ++nt)
        o[nt] = __builtin_amdgcn_mfma_f32_16x16x32_bf16(av[nt][k2], bp, o[nt], 0, 0, 0);
    }
    #pragma unroll
    for (int nt = 0; nt < 2; ++nt){
      uint2 t;
      t.x = pk2(o[nt][0], o[nt][1]);
      t.y = pk2(o[nt][2], o[nt][3]);
      *reinterpret_cast<uint2*>(&AO[i_r][h*32 + nt*16 + 4*g]) = t;
    }
  }
  __syncthreads();

  // ---- proj: 6 waves x 32 cols; A-frags from AO (LDS) ----
  {
    f32x4 pacc[4][2];
    #pragma unroll
    for (int mt = 0; mt < 4; ++mt){ pacc[mt][0] = z4; pacc[mt][1] = z4; }
    #pragma unroll
    for (int ks = 0; ks < 6; ++ks){
      bf16x8 a2[4];
      #pragma unroll
      for (int mt = 0; mt < 4; ++mt)
        a2[mt] = *reinterpret_cast<const bf16x8*>(&AO[mt*16 + r][ks*32 + 8*g]);
      #pragma unroll
      for (int nt = 0; nt < 2; ++nt){
        const bf16x8 bw = *reinterpret_cast<const bf16x8*>(wp + (size_t)(h*32 + nt*16 + r)*192 + ks*32 + 8*g);
        #pragma unroll
        for (int mt = 0; mt < 4; ++mt)
          pacc[mt][nt] = __builtin_amdgcn_mfma_f32_16x16x32_bf16(a2[mt], bw, pacc[mt][nt], 0, 0, 0);
      }
    }
    #pragma unroll
    for (int nt = 0; nt < 2; ++nt){
      const int n = h*32 + nt*16 + r;
      const float bias = pb[n];
      #pragma unroll
      for (int mt = 0; mt < 4; ++mt)
        #pragma unroll
        for (int jj = 0; jj < 4; ++jj){
          const int tok = mt*16 + 4*g + jj;
          if (tok < 49){
            const int ty = tok/7, tx = tok%7;
            int dh = wy*7 + ty + 3; if (dh >= 56) dh -= 56;
            int dw = wx*7 + tx + 3; if (dw >= 56) dw -= 56;
            out[(size_t)((bb*56 + dh)*56 + dw)*192 + n] = pacc[mt][nt][jj] + bias;
          }
        }
    }
  }
}

extern "C" void kernel_launch(void* const* d_in, const int* in_sizes, int n_in,
                              void* d_out, int out_size, void* d_ws, size_t ws_size,
                              hipStream_t stream) {
  const float* x     = (const float*)d_in[0];
  const float* rpb   = (const float*)d_in[1];
  const float* qkvw  = (const float*)d_in[2];
  const float* qkvb  = (const float*)d_in[3];
  const float* projw = (const float*)d_in[4];
  const float* projb = (const float*)d_in[5];
  float* out = (float*)d_out;

  char* ws = (char*)d_ws;
  u16*   wq    = (u16*)(ws);                                   // bf16 [576][192]
  u16*   wpj   = (u16*)(ws + 221184);                          // bf16 [192][192]
  float* biasC = (float*)(ws + 221184 + 73728);                // f32  [4][6][64][72]
  u16*   qG    = (u16*)(ws + 737280);                          // bf16 [12288][64][32]
  u16*   kG    = (u16*)(ws + 737280 + 1ll*50331648);           // bf16 [12288][64][32]
  u16*   vG    = (u16*)(ws + 737280 + 2ll*50331648);           // bf16 [12288][32][64]

  prep_kernel    <<<432, 256, 0, stream>>>(qkvw, projw, rpb, wq, wpj, biasC);
  qkv_kernel     <<<1024, 256, 0, stream>>>(x, wq, qkvb, qG, kG, vG);
  attnproj_kernel<<<2048, 384, 0, stream>>>(qG, kG, vG, biasC, wpj, projb, out);
}